// Round 1
// baseline (237.753 us; speedup 1.0000x reference)
//
#include <hip/hip_runtime.h>
#include <hip/hip_bf16.h>

#define N_ROWS 16384
#define C_COLS 2048
#define N_VIEWS 6
#define MOMENT_F 1.6384f   // N/10000
#define SEGS 128           // row segments for K1 parallelism

// ---------------------------------------------------------------------------
// K1: grid = N_VIEWS * SEGS blocks, 256 threads.
// Block (v,s): compact matching row indices of segment s into LDS, then
// stream those rows (float4 x2 per thread = all 2048 cols), accumulating
// sum and sum-of-squares in registers; finish with atomicAdd into the
// global (V, 2C) accumulator and a per-view count atomic.
// ---------------------------------------------------------------------------
__global__ __launch_bounds__(256) void k1_segstats(
    const float* __restrict__ x, const int* __restrict__ views,
    float* __restrict__ acc /* [2*V*C]: sums then sqsums */,
    float* __restrict__ counts /* [V] */,
    int L /* rows per segment */) {
  const int s = blockIdx.x / N_VIEWS;
  const int v = blockIdx.x % N_VIEWS;
  const int r0 = s * L;
  const int r1 = min(r0 + L, N_ROWS);
  const int len = r1 - r0;

  __shared__ int lds_list[2048];
  __shared__ int lds_cnt;
  if (threadIdx.x == 0) lds_cnt = 0;
  __syncthreads();

  for (int i = threadIdx.x; i < len; i += 256) {
    if (views[r0 + i] == v) {
      int p = atomicAdd(&lds_cnt, 1);
      lds_list[p] = r0 + i;
    }
  }
  __syncthreads();
  const int m = lds_cnt;
  const int t = threadIdx.x;

  float4 sA = {0.f, 0.f, 0.f, 0.f}, sB = {0.f, 0.f, 0.f, 0.f};
  float4 qA = {0.f, 0.f, 0.f, 0.f}, qB = {0.f, 0.f, 0.f, 0.f};

  for (int j = 0; j < m; ++j) {
    int r = lds_list[j];
    const float4* p = (const float4*)(x + (size_t)r * C_COLS);
    float4 a = p[t];        // cols 4t .. 4t+3
    float4 b = p[t + 256];  // cols 1024+4t .. 1024+4t+3
    sA.x += a.x; sA.y += a.y; sA.z += a.z; sA.w += a.w;
    sB.x += b.x; sB.y += b.y; sB.z += b.z; sB.w += b.w;
    qA.x = fmaf(a.x, a.x, qA.x); qA.y = fmaf(a.y, a.y, qA.y);
    qA.z = fmaf(a.z, a.z, qA.z); qA.w = fmaf(a.w, a.w, qA.w);
    qB.x = fmaf(b.x, b.x, qB.x); qB.y = fmaf(b.y, b.y, qB.y);
    qB.z = fmaf(b.z, b.z, qB.z); qB.w = fmaf(b.w, b.w, qB.w);
  }

  float* accSum = acc;
  float* accSq  = acc + N_VIEWS * C_COLS;
  const int cA = 4 * t;          // first float4's column base
  const int cB = 1024 + 4 * t;   // second float4's column base
  const int base = v * C_COLS;
  atomicAdd(&accSum[base + cA + 0], sA.x);
  atomicAdd(&accSum[base + cA + 1], sA.y);
  atomicAdd(&accSum[base + cA + 2], sA.z);
  atomicAdd(&accSum[base + cA + 3], sA.w);
  atomicAdd(&accSum[base + cB + 0], sB.x);
  atomicAdd(&accSum[base + cB + 1], sB.y);
  atomicAdd(&accSum[base + cB + 2], sB.z);
  atomicAdd(&accSum[base + cB + 3], sB.w);
  atomicAdd(&accSq[base + cA + 0], qA.x);
  atomicAdd(&accSq[base + cA + 1], qA.y);
  atomicAdd(&accSq[base + cA + 2], qA.z);
  atomicAdd(&accSq[base + cA + 3], qA.w);
  atomicAdd(&accSq[base + cB + 0], qB.x);
  atomicAdd(&accSq[base + cB + 1], qB.y);
  atomicAdd(&accSq[base + cB + 2], qB.z);
  atomicAdd(&accSq[base + cB + 3], qB.w);
  if (t == 0) atomicAdd(&counts[v], (float)m);
}

// ---------------------------------------------------------------------------
// K2: 8 blocks x 256 threads, one thread per column c.
// Finish means/stds, valid mask, new centers, cm/cs, per-column loss
// contribution; reduce and atomicAdd into d_out.
// ---------------------------------------------------------------------------
__global__ __launch_bounds__(256) void k2_finish(
    const float* __restrict__ acc, const float* __restrict__ counts,
    const float* __restrict__ cmean, const float* __restrict__ cstd,
    float* __restrict__ out) {
  const int c = blockIdx.x * 256 + threadIdx.x;

  float cnt[N_VIEWS];
  float nvalid = 0.f;
#pragma unroll
  for (int v = 0; v < N_VIEWS; ++v) {
    cnt[v] = counts[v];
    nvalid += (cnt[v] > 1.5f) ? 1.f : 0.f;
  }

  const float* accSum = acc;
  const float* accSq  = acc + N_VIEWS * C_COLS;
  float mean[N_VIEWS], sd[N_VIEWS];
  float nm = 0.f, ns = 0.f;
#pragma unroll
  for (int v = 0; v < N_VIEWS; ++v) {
    float su = accSum[v * C_COLS + c];
    float sq = accSq[v * C_COLS + c];
    float n = fmaxf(cnt[v], 1.f);
    float mu = su / n;
    float var = (sq - cnt[v] * mu * mu) / fmaxf(cnt[v] - 1.f, 1.f);
    float sdv = sqrtf(fmaxf(var, 0.f));
    mean[v] = mu;
    sd[v] = sdv;
    if (cnt[v] > 1.5f) { nm += mu; ns += sdv; }
  }
  nm /= nvalid;
  ns /= nvalid;
  const float cm = cmean[c] * (1.f - MOMENT_F) + nm * MOMENT_F;
  const float cs = cstd[c]  * (1.f - MOMENT_F) + ns * MOMENT_F;

  float contrib = 0.f;
#pragma unroll
  for (int v = 0; v < N_VIEWS; ++v) {
    if (cnt[v] > 1.5f) {
      float d1 = mean[v] - cm;
      float d2 = sd[v] - cs;
      contrib += d1 * d1 + d2 * d2;
    }
  }
  contrib /= (2.f * nvalid);

  // wave (64-lane) shuffle reduction, then cross-wave via LDS
  for (int o = 32; o > 0; o >>= 1) contrib += __shfl_down(contrib, o, 64);
  __shared__ float wsum[4];
  const int lane = threadIdx.x & 63;
  const int w = threadIdx.x >> 6;
  if (lane == 0) wsum[w] = contrib;
  __syncthreads();
  if (threadIdx.x == 0)
    atomicAdd(out, wsum[0] + wsum[1] + wsum[2] + wsum[3]);
}

extern "C" void kernel_launch(void* const* d_in, const int* in_sizes, int n_in,
                              void* d_out, int out_size, void* d_ws, size_t ws_size,
                              hipStream_t stream) {
  const float* x     = (const float*)d_in[0];  // (N, C) f32
  const float* cmean = (const float*)d_in[1];  // (C,)  f32
  const float* cstd  = (const float*)d_in[2];  // (C,)  f32
  const int*   views = (const int*)d_in[3];    // (N,)  i32
  float* out = (float*)d_out;

  // ws layout: [counts: 6 floats, padded to 256 B][acc: 2*V*C floats]
  float* counts = (float*)d_ws;
  float* acc    = (float*)((char*)d_ws + 256);
  const size_t zero_bytes = 256 + (size_t)2 * N_VIEWS * C_COLS * sizeof(float);

  hipMemsetAsync(d_ws, 0, zero_bytes, stream);
  hipMemsetAsync(d_out, 0, (size_t)out_size * sizeof(float), stream);

  const int L = (N_ROWS + SEGS - 1) / SEGS;  // 128 rows/segment
  k1_segstats<<<N_VIEWS * SEGS, 256, 0, stream>>>(x, views, acc, counts, L);
  k2_finish<<<C_COLS / 256, 256, 0, stream>>>(acc, counts, cmean, cstd, out);
}

// Round 2
// 210.979 us; speedup vs baseline: 1.1269x; 1.1269x over previous
//
#include <hip/hip_runtime.h>
#include <hip/hip_bf16.h>

#define N_ROWS 16384
#define C_COLS 2048
#define TWO_C 4096            // sums(2048) + sqsums(2048) per view
#define N_VIEWS 6
#define MOMENT_F 1.6384f      // N/10000
#define SEGS 128              // row segments for K1 parallelism
#define NCHUNK 8              // segment chunks for K1b parallelism
#define SEG_PER_CHUNK (SEGS / NCHUNK)

// acc layout: acc[v*TWO_C + c] = sum_v(col c), acc[v*TWO_C + 2048 + c] = sumsq
// part layout: part[(s*V+v)*TWO_C + ...] same per-slab layout, non-atomic.

// ---------------------------------------------------------------------------
// K1: grid = V*SEGS blocks, 256 thr. Compact matching rows into LDS, stream
// rows with float4 loads (4x unrolled -> 8 loads in flight), write per-block
// partial slab with plain coalesced stores (NO contended atomics).
// ---------------------------------------------------------------------------
__global__ __launch_bounds__(256) void k1_segstats(
    const float* __restrict__ x, const int* __restrict__ views,
    float* __restrict__ part, float* __restrict__ counts, int L) {
  const int s = blockIdx.x / N_VIEWS;
  const int v = blockIdx.x % N_VIEWS;
  const int r0 = s * L;
  const int len = min(L, N_ROWS - r0);

  __shared__ int lds_list[256];
  __shared__ int lds_cnt;
  if (threadIdx.x == 0) lds_cnt = 0;
  __syncthreads();
  for (int i = threadIdx.x; i < len; i += 256) {
    if (views[r0 + i] == v) {
      int p = atomicAdd(&lds_cnt, 1);
      lds_list[p] = r0 + i;
    }
  }
  __syncthreads();
  const int m = lds_cnt;
  const int t = threadIdx.x;

  float4 sA = {0.f,0.f,0.f,0.f}, sB = {0.f,0.f,0.f,0.f};
  float4 qA = {0.f,0.f,0.f,0.f}, qB = {0.f,0.f,0.f,0.f};

  int j = 0;
  for (; j + 4 <= m; j += 4) {
    int r0_ = lds_list[j], r1_ = lds_list[j+1];
    int r2_ = lds_list[j+2], r3_ = lds_list[j+3];
    const float4* p0 = (const float4*)(x + (size_t)r0_ * C_COLS);
    const float4* p1 = (const float4*)(x + (size_t)r1_ * C_COLS);
    const float4* p2 = (const float4*)(x + (size_t)r2_ * C_COLS);
    const float4* p3 = (const float4*)(x + (size_t)r3_ * C_COLS);
    float4 a0 = p0[t], b0 = p0[t+256];
    float4 a1 = p1[t], b1 = p1[t+256];
    float4 a2 = p2[t], b2 = p2[t+256];
    float4 a3 = p3[t], b3 = p3[t+256];
#define ACC(a,b) \
    sA.x += a.x; sA.y += a.y; sA.z += a.z; sA.w += a.w; \
    sB.x += b.x; sB.y += b.y; sB.z += b.z; sB.w += b.w; \
    qA.x = fmaf(a.x,a.x,qA.x); qA.y = fmaf(a.y,a.y,qA.y); \
    qA.z = fmaf(a.z,a.z,qA.z); qA.w = fmaf(a.w,a.w,qA.w); \
    qB.x = fmaf(b.x,b.x,qB.x); qB.y = fmaf(b.y,b.y,qB.y); \
    qB.z = fmaf(b.z,b.z,qB.z); qB.w = fmaf(b.w,b.w,qB.w);
    ACC(a0,b0) ACC(a1,b1) ACC(a2,b2) ACC(a3,b3)
  }
  for (; j < m; ++j) {
    int r = lds_list[j];
    const float4* p = (const float4*)(x + (size_t)r * C_COLS);
    float4 a = p[t], b = p[t+256];
    ACC(a,b)
  }
#undef ACC

  float4* slab = (float4*)(part + (size_t)(s * N_VIEWS + v) * TWO_C);
  slab[t]       = sA;   // sum, cols 4t..4t+3
  slab[t + 256] = sB;   // sum, cols 1024+4t..
  slab[t + 512] = qA;   // sq,  cols 4t..
  slab[t + 768] = qB;   // sq,  cols 1024+4t..
  if (t == 0) atomicAdd(&counts[v], (float)m);
}

// Fallback (ws too small): old contended-atomic accumulation, new acc layout.
__global__ __launch_bounds__(256) void k1_segstats_atomic(
    const float* __restrict__ x, const int* __restrict__ views,
    float* __restrict__ acc, float* __restrict__ counts, int L) {
  const int s = blockIdx.x / N_VIEWS;
  const int v = blockIdx.x % N_VIEWS;
  const int r0 = s * L;
  const int len = min(L, N_ROWS - r0);
  __shared__ int lds_list[256];
  __shared__ int lds_cnt;
  if (threadIdx.x == 0) lds_cnt = 0;
  __syncthreads();
  for (int i = threadIdx.x; i < len; i += 256)
    if (views[r0 + i] == v) lds_list[atomicAdd(&lds_cnt, 1)] = r0 + i;
  __syncthreads();
  const int m = lds_cnt;
  const int t = threadIdx.x;
  float4 sA = {0,0,0,0}, sB = {0,0,0,0}, qA = {0,0,0,0}, qB = {0,0,0,0};
  for (int j = 0; j < m; ++j) {
    const float4* p = (const float4*)(x + (size_t)lds_list[j] * C_COLS);
    float4 a = p[t], b = p[t+256];
    sA.x += a.x; sA.y += a.y; sA.z += a.z; sA.w += a.w;
    sB.x += b.x; sB.y += b.y; sB.z += b.z; sB.w += b.w;
    qA.x = fmaf(a.x,a.x,qA.x); qA.y = fmaf(a.y,a.y,qA.y);
    qA.z = fmaf(a.z,a.z,qA.z); qA.w = fmaf(a.w,a.w,qA.w);
    qB.x = fmaf(b.x,b.x,qB.x); qB.y = fmaf(b.y,b.y,qB.y);
    qB.z = fmaf(b.z,b.z,qB.z); qB.w = fmaf(b.w,b.w,qB.w);
  }
  float* base = acc + v * TWO_C;
  const int cA = 4 * t, cB = 1024 + 4 * t;
  atomicAdd(base+cA+0,sA.x); atomicAdd(base+cA+1,sA.y);
  atomicAdd(base+cA+2,sA.z); atomicAdd(base+cA+3,sA.w);
  atomicAdd(base+cB+0,sB.x); atomicAdd(base+cB+1,sB.y);
  atomicAdd(base+cB+2,sB.z); atomicAdd(base+cB+3,sB.w);
  atomicAdd(base+2048+cA+0,qA.x); atomicAdd(base+2048+cA+1,qA.y);
  atomicAdd(base+2048+cA+2,qA.z); atomicAdd(base+2048+cA+3,qA.w);
  atomicAdd(base+2048+cB+0,qB.x); atomicAdd(base+2048+cB+1,qB.y);
  atomicAdd(base+2048+cB+2,qB.z); atomicAdd(base+2048+cB+3,qB.w);
  if (t == 0) atomicAdd(&counts[v], (float)m);
}

// ---------------------------------------------------------------------------
// K1b: reduce partials over segments. Grid = NCHUNK*V*1024/256 = 192 blocks.
// Thread (chunk, v, c4) sums SEG_PER_CHUNK float4 partials, then 4 atomicAdds
// (NCHUNK-way contention only).
// ---------------------------------------------------------------------------
__global__ __launch_bounds__(256) void k1b_reduce(
    const float4* __restrict__ part4, float* __restrict__ acc) {
  const int u = blockIdx.x * 256 + threadIdx.x;
  const int chunk = u / (N_VIEWS * 1024);
  const int o = u % (N_VIEWS * 1024);
  const int v = o >> 10;
  const int c4 = o & 1023;
  float4 s = {0.f, 0.f, 0.f, 0.f};
  const int segBase = chunk * SEG_PER_CHUNK;
#pragma unroll
  for (int i = 0; i < SEG_PER_CHUNK; ++i) {
    float4 p = part4[(size_t)((segBase + i) * N_VIEWS + v) * 1024 + c4];
    s.x += p.x; s.y += p.y; s.z += p.z; s.w += p.w;
  }
  float* dst = acc + v * TWO_C + 4 * c4;
  atomicAdd(dst + 0, s.x);
  atomicAdd(dst + 1, s.y);
  atomicAdd(dst + 2, s.z);
  atomicAdd(dst + 3, s.w);
}

// ---------------------------------------------------------------------------
// K2: finish means/stds/new centers/loss; 8 blocks x 256 thr (one per column).
// ---------------------------------------------------------------------------
__global__ __launch_bounds__(256) void k2_finish(
    const float* __restrict__ acc, const float* __restrict__ counts,
    const float* __restrict__ cmean, const float* __restrict__ cstd,
    float* __restrict__ out) {
  const int c = blockIdx.x * 256 + threadIdx.x;

  float cnt[N_VIEWS];
  float nvalid = 0.f;
#pragma unroll
  for (int v = 0; v < N_VIEWS; ++v) {
    cnt[v] = counts[v];
    nvalid += (cnt[v] > 1.5f) ? 1.f : 0.f;
  }

  float mean[N_VIEWS], sd[N_VIEWS];
  float nm = 0.f, ns = 0.f;
#pragma unroll
  for (int v = 0; v < N_VIEWS; ++v) {
    float su = acc[v * TWO_C + c];
    float sq = acc[v * TWO_C + 2048 + c];
    float n = fmaxf(cnt[v], 1.f);
    float mu = su / n;
    float var = (sq - cnt[v] * mu * mu) / fmaxf(cnt[v] - 1.f, 1.f);
    float sdv = sqrtf(fmaxf(var, 0.f));
    mean[v] = mu;
    sd[v] = sdv;
    if (cnt[v] > 1.5f) { nm += mu; ns += sdv; }
  }
  nm /= nvalid;
  ns /= nvalid;
  const float cm = cmean[c] * (1.f - MOMENT_F) + nm * MOMENT_F;
  const float cs = cstd[c]  * (1.f - MOMENT_F) + ns * MOMENT_F;

  float contrib = 0.f;
#pragma unroll
  for (int v = 0; v < N_VIEWS; ++v) {
    if (cnt[v] > 1.5f) {
      float d1 = mean[v] - cm;
      float d2 = sd[v] - cs;
      contrib += d1 * d1 + d2 * d2;
    }
  }
  contrib /= (2.f * nvalid);

  for (int o = 32; o > 0; o >>= 1) contrib += __shfl_down(contrib, o, 64);
  __shared__ float wsum[4];
  const int lane = threadIdx.x & 63;
  const int w = threadIdx.x >> 6;
  if (lane == 0) wsum[w] = contrib;
  __syncthreads();
  if (threadIdx.x == 0)
    atomicAdd(out, wsum[0] + wsum[1] + wsum[2] + wsum[3]);
}

extern "C" void kernel_launch(void* const* d_in, const int* in_sizes, int n_in,
                              void* d_out, int out_size, void* d_ws, size_t ws_size,
                              hipStream_t stream) {
  const float* x     = (const float*)d_in[0];
  const float* cmean = (const float*)d_in[1];
  const float* cstd  = (const float*)d_in[2];
  const int*   views = (const int*)d_in[3];
  float* out = (float*)d_out;

  // ws layout: [counts: 6 floats, pad to 256 B][acc: V*TWO_C floats][partials]
  float* counts = (float*)d_ws;
  float* acc    = (float*)((char*)d_ws + 256);
  float* part   = acc + N_VIEWS * TWO_C;
  const size_t zero_bytes = 256 + (size_t)N_VIEWS * TWO_C * sizeof(float);
  const size_t need = zero_bytes +
      (size_t)SEGS * N_VIEWS * TWO_C * sizeof(float);  // ~12.7 MB

  hipMemsetAsync(d_ws, 0, zero_bytes, stream);
  hipMemsetAsync(d_out, 0, (size_t)out_size * sizeof(float), stream);

  const int L = N_ROWS / SEGS;  // 128
  if (ws_size >= need) {
    k1_segstats<<<N_VIEWS * SEGS, 256, 0, stream>>>(x, views, part, counts, L);
    k1b_reduce<<<NCHUNK * N_VIEWS * 1024 / 256, 256, 0, stream>>>(
        (const float4*)part, acc);
  } else {
    k1_segstats_atomic<<<N_VIEWS * SEGS, 256, 0, stream>>>(x, views, acc, counts, L);
  }
  k2_finish<<<C_COLS / 256, 256, 0, stream>>>(acc, counts, cmean, cstd, out);
}